// Round 2
// baseline (103.292 us; speedup 1.0000x reference)
//
#include <hip/hip_runtime.h>

// ImportancePoolingLayer: out[n,:] = sum_k wn[n,k] * x[neighbors[n,k], :]
// wn = weights / sum(weights)  (uniform 1/K if sum == 0)
// N = 50000, K = 32, D = 128. fp32 in/out.
// NOTE: harness passes integer inputs as int32 (NOT the reference's int64).
//
// One wave (64 lanes) per node: lane l owns columns {2l, 2l+1} (float2).
// Node index is wave-uniform; weights/neighbor rows load uniformly (scalar
// path), the x-row gathers are coalesced 512B wave accesses hitting L2/LLC
// (x is 25.6 MB < 256 MB LLC).

__global__ __launch_bounds__(256, 4) void importance_pool_kernel(
    const float* __restrict__ x,
    const float* __restrict__ w,
    const int* __restrict__ nbr,
    float* __restrict__ out,
    int N)
{
    constexpr int K = 32;
    constexpr int D = 128;

    const int lane = threadIdx.x & 63;
    int node = blockIdx.x * 4 + (threadIdx.x >> 6);
    if (node >= N) return;
    node = __builtin_amdgcn_readfirstlane(node);  // wave-uniform -> scalar regs

    const float* wrow = w   + (size_t)node * K;
    const int*   nrow = nbr + (size_t)node * K;

    // Load weights once; compute the sum for normalization.
    float wk[K];
    float s = 0.0f;
    #pragma unroll
    for (int k = 0; k < K; ++k) {
        wk[k] = wrow[k];
        s += wk[k];
    }

    const bool  zero = (s == 0.0f);
    const float inv  = zero ? 0.0f : (1.0f / s);
    const float uni  = 1.0f / (float)K;

    const int col = lane * 2;
    float ax = 0.0f, ay = 0.0f;

    #pragma unroll
    for (int k = 0; k < K; ++k) {
        const float wn  = zero ? uni : wk[k] * inv;
        const int   idx = nrow[k];
        const float2 v = *reinterpret_cast<const float2*>(
            x + (size_t)idx * D + col);
        ax = fmaf(wn, v.x, ax);
        ay = fmaf(wn, v.y, ay);
    }

    float2 r;
    r.x = ax;
    r.y = ay;
    *reinterpret_cast<float2*>(out + (size_t)node * D + col) = r;
}

extern "C" void kernel_launch(void* const* d_in, const int* in_sizes, int n_in,
                              void* d_out, int out_size, void* d_ws, size_t ws_size,
                              hipStream_t stream) {
    const float* x   = (const float*)d_in[0];
    const float* w   = (const float*)d_in[1];
    const int*   nbr = (const int*)d_in[2];
    float*       out = (float*)d_out;

    const int K = 32;
    const int N = in_sizes[1] / K;          // weights is [N, K]

    const int nodes_per_block = 4;           // 4 waves of 64
    const int blocks = (N + nodes_per_block - 1) / nodes_per_block;
    importance_pool_kernel<<<blocks, 256, 0, stream>>>(x, w, nbr, out, N);
}